// Round 4
// baseline (995.395 us; speedup 1.0000x reference)
//
#include <hip/hip_runtime.h>

#define NN 100000
#define NE 1600000
#define NG 128
#define BN_EPS 1e-5f
#define NBKT 64

typedef short s16x8 __attribute__((ext_vector_type(8)));
typedef float f32x4 __attribute__((ext_vector_type(4)));

static __device__ __forceinline__ unsigned short f2bf(float f) {
    unsigned u = __float_as_uint(f);
    u += 0x7fffu + ((u >> 16) & 1u);   // RNE
    return (unsigned short)(u >> 16);
}
static __device__ __forceinline__ unsigned packbf(float a, float b) {
    return (unsigned)f2bf(a) | ((unsigned)f2bf(b) << 16);
}
static __device__ __forceinline__ float bf_lo(unsigned u) { return __uint_as_float(u << 16); }
static __device__ __forceinline__ float bf_hi(unsigned u) { return __uint_as_float(u & 0xffff0000u); }

// ---------------- degree histogram ----------------
__global__ __launch_bounds__(256) void k_hist(const int* __restrict__ dst, int* __restrict__ deg) {
    int e = blockIdx.x * 256 + threadIdx.x;
    if (e < NE) atomicAdd(&deg[dst[e]], 1);
}

__global__ __launch_bounds__(256) void k_dinv(const int* __restrict__ deg, float* __restrict__ dinv) {
    int n = blockIdx.x * 256 + threadIdx.x;
    if (n < NN) dinv[n] = rsqrtf((float)deg[n] + 1.0f);
}

// ---------------- prefix scan over deg -> row_start ----------------
__global__ __launch_bounds__(256) void k_blockscan(const int* __restrict__ deg, int* __restrict__ excl,
                                                   int* __restrict__ bsum) {
    __shared__ int s[256];
    int t = threadIdx.x;
    int i = blockIdx.x * 256 + t;
    int v = (i < NN) ? deg[i] : 0;
    s[t] = v;
    __syncthreads();
    for (int o = 1; o < 256; o <<= 1) {
        int add = (t >= o) ? s[t - o] : 0;
        __syncthreads();
        s[t] += add;
        __syncthreads();
    }
    if (i < NN) excl[i] = s[t] - v;
    if (t == 255) bsum[blockIdx.x] = s[255];
}

__global__ __launch_bounds__(512) void k_scanb(int* __restrict__ bsum, int nb, int* __restrict__ row_start) {
    __shared__ int s[512];
    int t = threadIdx.x;
    int v = (t < nb) ? bsum[t] : 0;
    s[t] = v;
    __syncthreads();
    for (int o = 1; o < 512; o <<= 1) {
        int add = (t >= o) ? s[t - o] : 0;
        __syncthreads();
        s[t] += add;
        __syncthreads();
    }
    if (t < nb) bsum[t] = s[t] - v;
    if (t == nb - 1) row_start[NN] = s[t];
}

__global__ __launch_bounds__(256) void k_scanadd(int* __restrict__ row_start, const int* __restrict__ bsum) {
    int i = blockIdx.x * 256 + threadIdx.x;
    if (i < NN) row_start[i] += bsum[blockIdx.x];
}

// ---------------- CSR fill ----------------
__global__ __launch_bounds__(256) void k_fill(const int* __restrict__ src, const int* __restrict__ dst,
                                              const float* __restrict__ dinv, const int* __restrict__ row_start,
                                              int* __restrict__ cursor, int2* __restrict__ epair) {
    int e = blockIdx.x * 256 + threadIdx.x;
    if (e >= NE) return;
    int s = src[e], d = dst[e];
    float cf = dinv[s] * dinv[d];
    int pos = row_start[d] + atomicAdd(&cursor[d], 1);
    epair[pos] = make_int2(s, __float_as_int(cf));
}

// ---------------- x -> bf16 cast ----------------
__global__ __launch_bounds__(256) void k_cast(const float* __restrict__ x, uint4* __restrict__ xb) {
    int i = blockIdx.x * 256 + threadIdx.x;   // 1.6M groups of 8 floats
    if (i >= NN * 16) return;
    float4 a = *(const float4*)(x + (size_t)i * 8);
    float4 b = *(const float4*)(x + (size_t)i * 8 + 4);
    uint4 o;
    o.x = packbf(a.x, a.y);
    o.y = packbf(a.z, a.w);
    o.z = packbf(b.x, b.y);
    o.w = packbf(b.z, b.w);
    xb[i] = o;
}

// ---------------- W -> MFMA fragment order (bf16) ----------------
__global__ __launch_bounds__(64) void k_wfrag(const float* __restrict__ W, ushort* __restrict__ Wf) {
    int unit = blockIdx.x;          // 0..31: ks = unit>>3, nb = unit&7
    int lane = threadIdx.x;
    int ks = unit >> 3, nb = unit & 7;
    int n = nb * 16 + (lane & 15);
    int k0 = ks * 32 + (lane >> 4) * 8;
    ushort o[8];
#pragma unroll
    for (int j = 0; j < 8; ++j) o[j] = f2bf(W[(size_t)(k0 + j) * 128 + n]);
    ushort* p = Wf + ((size_t)unit * 64 + lane) * 8;
#pragma unroll
    for (int j = 0; j < 8; ++j) p[j] = o[j];
}

// ---------------- MFMA GEMM: hm_bf16[N][128] = Xb_bf16[N][128] @ W ----------------
__global__ __launch_bounds__(256) void k_gemm(const ushort* __restrict__ Xb, const ushort* __restrict__ Wf,
                                              ushort* __restrict__ hm) {
    int tid = threadIdx.x;
    int wid = tid >> 6, lane = tid & 63;
    int r0 = blockIdx.x * 64 + wid * 16;
    int m = lane & 15, g = lane >> 4;
    int xrow = r0 + m;
    int xr = (xrow < NN) ? xrow : (NN - 1);
    const ushort* Xrow = Xb + (size_t)xr * 128 + g * 8;
    f32x4 acc[8];
#pragma unroll
    for (int nb = 0; nb < 8; ++nb) acc[nb] = (f32x4){0.f, 0.f, 0.f, 0.f};
#pragma unroll
    for (int ks = 0; ks < 4; ++ks) {
        s16x8 af = *(const s16x8*)(Xrow + ks * 32);
#pragma unroll
        for (int nb = 0; nb < 8; ++nb) {
            s16x8 wf = *(const s16x8*)(Wf + ((size_t)(ks * 8 + nb) * 64 + lane) * 8);
            acc[nb] = __builtin_amdgcn_mfma_f32_16x16x32_bf16(wf, af, acc[nb], 0, 0, 0);
        }
    }
    if (xrow < NN) {
        ushort* orow = hm + (size_t)xrow * 128 + g * 4;
#pragma unroll
        for (int nb = 0; nb < 8; ++nb) {
            ushort4 o;
            o.x = f2bf(acc[nb][0]);
            o.y = f2bf(acc[nb][1]);
            o.z = f2bf(acc[nb][2]);
            o.w = f2bf(acc[nb][3]);
            *(ushort4*)(orow + nb * 16) = o;
        }
    }
}

// ---------------- aggregate + bias + relu + fused BN stats ----------------
// ONE WAVE PER NODE: lane covers 2 channels (dword of the 256B bf16 row).
// Edges consumed in chunks of 16: cooperative epair load (lanes 0..15),
// readlane -> SGPR index -> coalesced 256B gather, 16 outstanding per wave.
__global__ __launch_bounds__(256) void k_agg(const uint* __restrict__ hm32, const int2* __restrict__ epair,
                                             const int* __restrict__ rs, const float* __restrict__ dinv,
                                             const float* __restrict__ bias, float* __restrict__ act,
                                             float* __restrict__ bnsum, float* __restrict__ bnsq) {
    int tid = threadIdx.x;
    int lane = tid & 63;
    int n = blockIdx.x * 4 + (tid >> 6);   // grid = NN/4 = 25000 blocks, exact

    float di = dinv[n];
    float sc = di * di;
    uint self = hm32[(size_t)n * 64 + lane];
    float a0 = sc * bf_lo(self);
    float a1 = sc * bf_hi(self);

    int i  = __builtin_amdgcn_readfirstlane(rs[n]);
    int i1 = __builtin_amdgcn_readfirstlane(rs[n + 1]);

    int2 epv = make_int2(0, 0);
    if (i < i1) {
        int o = min(min(lane, 15), i1 - i - 1);
        epv = epair[i + o];
    }

    while (i < i1) {
        int cnt = i1 - i;
        cnt = (cnt > 16) ? 16 : cnt;       // wave-uniform
        int2 cur = epv;
        int inext = i + cnt;
        if (inext < i1) {                   // prefetch next chunk while gathers fly
            int o = min(min(lane, 15), i1 - inext - 1);
            epv = epair[inext + o];
        }
        uint g[16];
#pragma unroll
        for (int u = 0; u < 16; ++u) {
            int sidx = __builtin_amdgcn_readlane(cur.x, min(u, cnt - 1));
            g[u] = hm32[(size_t)sidx * 64 + lane];
        }
#pragma unroll
        for (int u = 0; u < 16; ++u) {
            float c = __int_as_float(__builtin_amdgcn_readlane(cur.y, min(u, cnt - 1)));
            c = (u < cnt) ? c : 0.f;        // zero out padded slots
            a0 += c * bf_lo(g[u]);
            a1 += c * bf_hi(g[u]);
        }
        i = inext;
    }

    float2 b2 = *(const float2*)(bias + lane * 2);
    float z0 = fmaxf(a0 + b2.x, 0.f);
    float z1 = fmaxf(a1 + b2.y, 0.f);
    *(float2*)(act + (size_t)n * 128 + lane * 2) = make_float2(z0, z1);

    int bkt = blockIdx.x & (NBKT - 1);
    atomicAdd(&bnsum[bkt * 128 + lane * 2],     z0);
    atomicAdd(&bnsum[bkt * 128 + lane * 2 + 1], z1);
    atomicAdd(&bnsq[bkt * 128 + lane * 2],      z0 * z0);
    atomicAdd(&bnsq[bkt * 128 + lane * 2 + 1],  z1 * z1);
}

// ---------------- normalize + write h_cat + pool + bf16 X for next layer ----------------
__global__ __launch_bounds__(128) void k_norm(const float* __restrict__ act, const float* __restrict__ bnsum,
                                              const float* __restrict__ bnsq, const float* __restrict__ gam,
                                              const float* __restrict__ bet, const int* __restrict__ batch,
                                              float* __restrict__ out, float* __restrict__ gout, int lofs,
                                              ushort* __restrict__ xb) {
    int c = threadIdx.x;
    int n0 = blockIdx.x * 64;
    if (n0 >= NN) return;
    int n1 = n0 + 64; if (n1 > NN) n1 = NN;
    float s = 0.f, q = 0.f;
#pragma unroll
    for (int k = 0; k < NBKT; ++k) {
        s += bnsum[k * 128 + c];
        q += bnsq[k * 128 + c];
    }
    float mean = s / (float)NN;
    float var = q / (float)NN - mean * mean;
    float rstd = rsqrtf(fmaxf(var, 0.f) + BN_EPS);
    float scale = gam[c] * rstd;
    float shift = bet[c] - mean * scale;
    int cur = batch[n0];
    float acc = 0.f;
    for (int n = n0; n < n1; ++n) {
        float z = act[(size_t)n * 128 + c] * scale + shift;
        out[(size_t)n * 384 + lofs + c] = z;
        if (xb) xb[(size_t)n * 128 + c] = f2bf(z);
        int bn = batch[n];
        if (bn != cur) {
            atomicAdd(&gout[(size_t)cur * 384 + lofs + c], acc);
            acc = 0.f;
            cur = bn;
        }
        acc += z;
    }
    atomicAdd(&gout[(size_t)cur * 384 + lofs + c], acc);
}

extern "C" void kernel_launch(void* const* d_in, const int* in_sizes, int n_in,
                              void* d_out, int out_size, void* d_ws, size_t ws_size,
                              hipStream_t stream) {
    const float* x = (const float*)d_in[0];
    const int* ei = (const int*)d_in[1];
    const int* src = ei;
    const int* dst = ei + NE;
    const int* batch = (const int*)d_in[2];
    const float *W[3], *b[3], *g[3], *beta[3];
    for (int l = 0; l < 3; ++l) {
        W[l]    = (const float*)d_in[3 + 4 * l];
        b[l]    = (const float*)d_in[4 + 4 * l];
        g[l]    = (const float*)d_in[5 + 4 * l];
        beta[l] = (const float*)d_in[6 + 4 * l];
    }
    float* out = (float*)d_out;
    float* gout = out + (size_t)NN * 384;

    char* ws = (char*)d_ws;
    size_t off = 0;
    auto alloc = [&](size_t bytes) -> char* {
        off = (off + 255) & ~(size_t)255;
        char* p = ws + off;
        off += bytes;
        return p;
    };
    ushort* hx       = (ushort*)alloc((size_t)NN * 256);      // bf16 rows: X input AND gemm output (aliased)
    float*  act      = (float*)alloc((size_t)NN * 128 * 4);
    int2*   epair    = (int2*)alloc((size_t)NE * 8);
    int*    deg      = (int*)alloc((size_t)NN * 4);
    int*    cursor   = (int*)alloc((size_t)NN * 4);
    int*    row_start= (int*)alloc((size_t)(NN + 1) * 4);
    float*  dinv     = (float*)alloc((size_t)NN * 4);
    int*    bsum     = (int*)alloc(512 * 4);
    float*  bnst     = (float*)alloc((size_t)3 * 2 * NBKT * 128 * 4);   // [layer][sum|sq][NBKT][128]
    ushort* Wf       = (ushort*)alloc(3 * 16384 * 2);
    (void)ws_size;

    hipMemsetAsync(deg, 0, (size_t)NN * 4, stream);
    hipMemsetAsync(cursor, 0, (size_t)NN * 4, stream);
    hipMemsetAsync(bnst, 0, (size_t)3 * 2 * NBKT * 128 * 4, stream);
    hipMemsetAsync(gout, 0, (size_t)NG * 384 * 4, stream);

    int nbN = (NN + 255) / 256;     // 391
    int nbE = (NE + 255) / 256;     // 6250

    k_hist<<<nbE, 256, 0, stream>>>(dst, deg);
    k_dinv<<<nbN, 256, 0, stream>>>(deg, dinv);
    k_blockscan<<<nbN, 256, 0, stream>>>(deg, row_start, bsum);
    k_scanb<<<1, 512, 0, stream>>>(bsum, nbN, row_start);
    k_scanadd<<<nbN, 256, 0, stream>>>(row_start, bsum);
    k_fill<<<nbE, 256, 0, stream>>>(src, dst, dinv, row_start, cursor, epair);
    k_cast<<<(NN * 16 + 255) / 256, 256, 0, stream>>>(x, (uint4*)hx);
    for (int l = 0; l < 3; ++l) k_wfrag<<<32, 64, 0, stream>>>(W[l], Wf + l * 16384);

    for (int l = 0; l < 3; ++l) {
        float* S = bnst + (size_t)l * 2 * NBKT * 128;
        float* Q = S + NBKT * 128;
        k_gemm<<<(NN + 63) / 64, 256, 0, stream>>>(hx, Wf + l * 16384, hx);
        k_agg<<<NN / 4, 256, 0, stream>>>((const uint*)hx, epair, row_start, dinv, b[l], act, S, Q);
        k_norm<<<(NN + 63) / 64, 128, 0, stream>>>(act, S, Q, g[l], beta[l], batch, out, gout, l * 128,
                                                   (l < 2) ? hx : (ushort*)nullptr);
    }
}

// Round 5
// 556.721 us; speedup vs baseline: 1.7880x; 1.7880x over previous
//
#include <hip/hip_runtime.h>

#define NN 100000
#define NE 1600000
#define NG 128
#define BN_EPS 1e-5f
#define NBKT 64
#define AGG_BLOCKS 2048
#define AGG_WAVES (AGG_BLOCKS * 4)

typedef short s16x8 __attribute__((ext_vector_type(8)));
typedef float f32x4 __attribute__((ext_vector_type(4)));

static __device__ __forceinline__ unsigned short f2bf(float f) {
    unsigned u = __float_as_uint(f);
    u += 0x7fffu + ((u >> 16) & 1u);   // RNE
    return (unsigned short)(u >> 16);
}
static __device__ __forceinline__ unsigned packbf(float a, float b) {
    return (unsigned)f2bf(a) | ((unsigned)f2bf(b) << 16);
}
static __device__ __forceinline__ float bf_lo(unsigned u) { return __uint_as_float(u << 16); }
static __device__ __forceinline__ float bf_hi(unsigned u) { return __uint_as_float(u & 0xffff0000u); }
static __device__ __forceinline__ float bf2f(ushort u) { return __uint_as_float((unsigned)u << 16); }

// ---------------- degree histogram ----------------
__global__ __launch_bounds__(256) void k_hist(const int* __restrict__ dst, int* __restrict__ deg) {
    int e = blockIdx.x * 256 + threadIdx.x;
    if (e < NE) atomicAdd(&deg[dst[e]], 1);
}

__global__ __launch_bounds__(256) void k_dinv(const int* __restrict__ deg, float* __restrict__ dinv) {
    int n = blockIdx.x * 256 + threadIdx.x;
    if (n < NN) dinv[n] = rsqrtf((float)deg[n] + 1.0f);
}

// ---------------- prefix scan over deg -> row_start ----------------
__global__ __launch_bounds__(256) void k_blockscan(const int* __restrict__ deg, int* __restrict__ excl,
                                                   int* __restrict__ bsum) {
    __shared__ int s[256];
    int t = threadIdx.x;
    int i = blockIdx.x * 256 + t;
    int v = (i < NN) ? deg[i] : 0;
    s[t] = v;
    __syncthreads();
    for (int o = 1; o < 256; o <<= 1) {
        int add = (t >= o) ? s[t - o] : 0;
        __syncthreads();
        s[t] += add;
        __syncthreads();
    }
    if (i < NN) excl[i] = s[t] - v;
    if (t == 255) bsum[blockIdx.x] = s[255];
}

__global__ __launch_bounds__(512) void k_scanb(int* __restrict__ bsum, int nb, int* __restrict__ row_start) {
    __shared__ int s[512];
    int t = threadIdx.x;
    int v = (t < nb) ? bsum[t] : 0;
    s[t] = v;
    __syncthreads();
    for (int o = 1; o < 512; o <<= 1) {
        int add = (t >= o) ? s[t - o] : 0;
        __syncthreads();
        s[t] += add;
        __syncthreads();
    }
    if (t < nb) bsum[t] = s[t] - v;
    if (t == nb - 1) row_start[NN] = s[t];
}

__global__ __launch_bounds__(256) void k_scanadd(int* __restrict__ row_start, const int* __restrict__ bsum) {
    int i = blockIdx.x * 256 + threadIdx.x;
    if (i < NN) row_start[i] += bsum[blockIdx.x];
}

// ---------------- CSR fill ----------------
__global__ __launch_bounds__(256) void k_fill(const int* __restrict__ src, const int* __restrict__ dst,
                                              const float* __restrict__ dinv, const int* __restrict__ row_start,
                                              int* __restrict__ cursor, int2* __restrict__ epair) {
    int e = blockIdx.x * 256 + threadIdx.x;
    if (e >= NE) return;
    int s = src[e], d = dst[e];
    float cf = dinv[s] * dinv[d];
    int pos = row_start[d] + atomicAdd(&cursor[d], 1);
    epair[pos] = make_int2(s, __float_as_int(cf));
}

// ---------------- x -> bf16 cast ----------------
__global__ __launch_bounds__(256) void k_cast(const float* __restrict__ x, uint4* __restrict__ xb) {
    int i = blockIdx.x * 256 + threadIdx.x;   // 1.6M groups of 8 floats
    if (i >= NN * 16) return;
    float4 a = *(const float4*)(x + (size_t)i * 8);
    float4 b = *(const float4*)(x + (size_t)i * 8 + 4);
    uint4 o;
    o.x = packbf(a.x, a.y);
    o.y = packbf(a.z, a.w);
    o.z = packbf(b.x, b.y);
    o.w = packbf(b.z, b.w);
    xb[i] = o;
}

// ---------------- W -> MFMA fragment order (bf16) ----------------
// Wf[((ks*8+nb)*64 + lane)*8 + j] = bf16(W[ks*32 + (lane>>4)*8 + j][nb*16 + (lane&15)])
__global__ __launch_bounds__(64) void k_wfrag(const float* __restrict__ W, ushort* __restrict__ Wf) {
    int unit = blockIdx.x;          // 0..31: ks = unit>>3, nb = unit&7
    int lane = threadIdx.x;
    int ks = unit >> 3, nb = unit & 7;
    int n = nb * 16 + (lane & 15);
    int k0 = ks * 32 + (lane >> 4) * 8;
    ushort o[8];
#pragma unroll
    for (int j = 0; j < 8; ++j) o[j] = f2bf(W[(size_t)(k0 + j) * 128 + n]);
    ushort* p = Wf + ((size_t)unit * 64 + lane) * 8;
#pragma unroll
    for (int j = 0; j < 8; ++j) p[j] = o[j];
}

// ---------------- fold BN scale into W fragments: Wff = diag(s) * W (bf16) ----------------
__global__ __launch_bounds__(64) void k_wscale(const ushort* __restrict__ Wfb, const float* __restrict__ svec,
                                               ushort* __restrict__ Wff) {
    int unit = blockIdx.x;
    int lane = threadIdx.x;
    int k0 = (unit >> 3) * 32 + (lane >> 4) * 8;
    const ushort* p = Wfb + ((size_t)unit * 64 + lane) * 8;
    ushort* o = Wff + ((size_t)unit * 64 + lane) * 8;
#pragma unroll
    for (int j = 0; j < 8; ++j) o[j] = f2bf(bf2f(p[j]) * svec[k0 + j]);
}

// ---------------- BN stats -> (scale, shift), and tW = shift^T @ Wnext ----------------
__global__ __launch_bounds__(128) void k_finalize(const float* __restrict__ S, const float* __restrict__ Q,
                                                  const float* __restrict__ gam, const float* __restrict__ bet,
                                                  float* __restrict__ svec, float* __restrict__ tvec,
                                                  const float* __restrict__ Wnext, float* __restrict__ tW) {
    __shared__ float ts[128];
    int c = threadIdx.x;
    float s = 0.f, q = 0.f;
    for (int k = 0; k < NBKT; ++k) {
        s += S[k * 128 + c];
        q += Q[k * 128 + c];
    }
    float mean = s / (float)NN;
    float var = q / (float)NN - mean * mean;
    float rstd = rsqrtf(fmaxf(var, 0.f) + BN_EPS);
    float sc = gam[c] * rstd;
    float sh = bet[c] - mean * sc;
    svec[c] = sc;
    tvec[c] = sh;
    ts[c] = sh;
    __syncthreads();
    if (Wnext) {
        float acc = 0.f;
        for (int k = 0; k < 128; ++k) acc += ts[k] * Wnext[(size_t)k * 128 + c];
        tW[c] = acc;
    }
}

// ---------------- MFMA GEMM: hm_bf16[N][128] = Xb_bf16[N][128] @ Wf (+ tW row vector) ----------------
__global__ __launch_bounds__(256) void k_gemm(const ushort* __restrict__ Xb, const ushort* __restrict__ Wf,
                                              const float* __restrict__ tW, ushort* __restrict__ hm) {
    int tid = threadIdx.x;
    int wid = tid >> 6, lane = tid & 63;
    int r0 = blockIdx.x * 64 + wid * 16;
    int m = lane & 15, g = lane >> 4;
    int xrow = r0 + m;
    int xr = (xrow < NN) ? xrow : (NN - 1);
    const ushort* Xrow = Xb + (size_t)xr * 128 + g * 8;
    f32x4 acc[8];
#pragma unroll
    for (int nb = 0; nb < 8; ++nb) acc[nb] = (f32x4){0.f, 0.f, 0.f, 0.f};
#pragma unroll
    for (int ks = 0; ks < 4; ++ks) {
        s16x8 af = *(const s16x8*)(Xrow + ks * 32);
#pragma unroll
        for (int nb = 0; nb < 8; ++nb) {
            s16x8 wf = *(const s16x8*)(Wf + ((size_t)(ks * 8 + nb) * 64 + lane) * 8);
            acc[nb] = __builtin_amdgcn_mfma_f32_16x16x32_bf16(wf, af, acc[nb], 0, 0, 0);
        }
    }
    if (xrow < NN) {
        ushort* orow = hm + (size_t)xrow * 128 + g * 4;
        if (tW) {
#pragma unroll
            for (int nb = 0; nb < 8; ++nb) {
                float4 tw = *(const float4*)(tW + nb * 16 + g * 4);
                ushort4 o;
                o.x = f2bf(acc[nb][0] + tw.x);
                o.y = f2bf(acc[nb][1] + tw.y);
                o.z = f2bf(acc[nb][2] + tw.z);
                o.w = f2bf(acc[nb][3] + tw.w);
                *(ushort4*)(orow + nb * 16) = o;
            }
        } else {
#pragma unroll
            for (int nb = 0; nb < 8; ++nb) {
                ushort4 o;
                o.x = f2bf(acc[nb][0]);
                o.y = f2bf(acc[nb][1]);
                o.z = f2bf(acc[nb][2]);
                o.w = f2bf(acc[nb][3]);
                *(ushort4*)(orow + nb * 16) = o;
            }
        }
    }
}

// ---------------- aggregate + bias + relu + fused BN stats ----------------
// Persistent: one wave per node per iteration; lane covers 2 channels (dword of 256B row).
// Per-thread stat registers across nodes -> LDS reduce -> bucketed global atomics.
__global__ __launch_bounds__(256) void k_agg(const uint* __restrict__ hm32, const int2* __restrict__ epair,
                                             const int* __restrict__ rs, const float* __restrict__ dinv,
                                             const float* __restrict__ bias, uint* __restrict__ act,
                                             float* __restrict__ bnsum, float* __restrict__ bnsq) {
    __shared__ float ls[128], lq[128];
    int tid = threadIdx.x;
    if (tid < 128) { ls[tid] = 0.f; lq[tid] = 0.f; }
    __syncthreads();
    int lane = tid & 63;
    int wgid = blockIdx.x * 4 + (tid >> 6);
    float2 b2 = *(const float2*)(bias + lane * 2);
    float s0 = 0.f, s1 = 0.f, q0 = 0.f, q1 = 0.f;

    for (int n = wgid; n < NN; n += AGG_WAVES) {
        float di = dinv[n];
        float sc = di * di;
        uint self = hm32[(size_t)n * 64 + lane];
        float a0 = sc * bf_lo(self);
        float a1 = sc * bf_hi(self);

        int i  = __builtin_amdgcn_readfirstlane(rs[n]);
        int i1 = __builtin_amdgcn_readfirstlane(rs[n + 1]);

        int2 epv = make_int2(0, 0);
        if (i < i1) {
            int o = min(min(lane, 15), i1 - i - 1);
            epv = epair[i + o];
        }
        while (i < i1) {
            int cnt = i1 - i;
            cnt = (cnt > 16) ? 16 : cnt;       // wave-uniform
            int2 cur = epv;
            int inext = i + cnt;
            if (inext < i1) {                   // prefetch next chunk while gathers fly
                int o = min(min(lane, 15), i1 - inext - 1);
                epv = epair[inext + o];
            }
            uint g[16];
#pragma unroll
            for (int u = 0; u < 16; ++u) {
                int sidx = __builtin_amdgcn_readlane(cur.x, min(u, cnt - 1));
                g[u] = hm32[(size_t)sidx * 64 + lane];
            }
#pragma unroll
            for (int u = 0; u < 16; ++u) {
                float c = __int_as_float(__builtin_amdgcn_readlane(cur.y, min(u, cnt - 1)));
                c = (u < cnt) ? c : 0.f;
                a0 += c * bf_lo(g[u]);
                a1 += c * bf_hi(g[u]);
            }
            i = inext;
        }
        float z0 = fmaxf(a0 + b2.x, 0.f);
        float z1 = fmaxf(a1 + b2.y, 0.f);
        act[(size_t)n * 64 + lane] = packbf(z0, z1);
        s0 += z0; s1 += z1;
        q0 += z0 * z0; q1 += z1 * z1;
    }
    atomicAdd(&ls[lane * 2],     s0);
    atomicAdd(&ls[lane * 2 + 1], s1);
    atomicAdd(&lq[lane * 2],     q0);
    atomicAdd(&lq[lane * 2 + 1], q1);
    __syncthreads();
    if (tid < 128) {
        int bkt = blockIdx.x & (NBKT - 1);
        atomicAdd(&bnsum[bkt * 128 + tid], ls[tid]);
        atomicAdd(&bnsq[bkt * 128 + tid],  lq[tid]);
    }
}

// ---------------- normalize + write h_cat + pool ----------------
__global__ __launch_bounds__(128) void k_norm(const ushort* __restrict__ act, const float* __restrict__ svec,
                                              const float* __restrict__ tvec, const int* __restrict__ batch,
                                              float* __restrict__ out, float* __restrict__ gout, int lofs) {
    int c = threadIdx.x;
    int n0 = blockIdx.x * 64;
    if (n0 >= NN) return;
    int n1 = n0 + 64; if (n1 > NN) n1 = NN;
    float scale = svec[c];
    float shift = tvec[c];
    int cur = batch[n0];
    float acc = 0.f;
    for (int n = n0; n < n1; ++n) {
        float z = bf2f(act[(size_t)n * 128 + c]) * scale + shift;
        out[(size_t)n * 384 + lofs + c] = z;
        int bn = batch[n];
        if (bn != cur) {
            atomicAdd(&gout[(size_t)cur * 384 + lofs + c], acc);
            acc = 0.f;
            cur = bn;
        }
        acc += z;
    }
    atomicAdd(&gout[(size_t)cur * 384 + lofs + c], acc);
}

extern "C" void kernel_launch(void* const* d_in, const int* in_sizes, int n_in,
                              void* d_out, int out_size, void* d_ws, size_t ws_size,
                              hipStream_t stream) {
    const float* x = (const float*)d_in[0];
    const int* ei = (const int*)d_in[1];
    const int* src = ei;
    const int* dst = ei + NE;
    const int* batch = (const int*)d_in[2];
    const float *W[3], *b[3], *g[3], *beta[3];
    for (int l = 0; l < 3; ++l) {
        W[l]    = (const float*)d_in[3 + 4 * l];
        b[l]    = (const float*)d_in[4 + 4 * l];
        g[l]    = (const float*)d_in[5 + 4 * l];
        beta[l] = (const float*)d_in[6 + 4 * l];
    }
    float* out = (float*)d_out;
    float* gout = out + (size_t)NN * 384;

    char* ws = (char*)d_ws;
    size_t off = 0;
    auto alloc = [&](size_t bytes) -> char* {
        off = (off + 255) & ~(size_t)255;
        char* p = ws + off;
        off += bytes;
        return p;
    };
    ushort* xb       = (ushort*)alloc((size_t)NN * 256);      // bf16 x
    ushort* act      = (ushort*)alloc((size_t)NN * 256);      // bf16 relu output (pre-BN)
    ushort* hm       = (ushort*)alloc((size_t)NN * 256);      // bf16 gemm output
    int2*   epair    = (int2*)alloc((size_t)NE * 8);
    int*    deg      = (int*)alloc((size_t)NN * 4);
    int*    cursor   = (int*)alloc((size_t)NN * 4);
    int*    row_start= (int*)alloc((size_t)(NN + 1) * 4);
    float*  dinv     = (float*)alloc((size_t)NN * 4);
    int*    bsum     = (int*)alloc(512 * 4);
    float*  bnst     = (float*)alloc((size_t)3 * 2 * NBKT * 128 * 4);   // [layer][sum|sq][NBKT][128]
    ushort* Wf       = (ushort*)alloc(3 * 16384 * 2);
    ushort* Wff      = (ushort*)alloc(16384 * 2);
    float*  svt      = (float*)alloc(3 * 2 * 128 * 4);                  // [layer][s|t][128]
    float*  tW       = (float*)alloc(128 * 4);
    (void)ws_size;

    hipMemsetAsync(deg, 0, (size_t)NN * 4, stream);
    hipMemsetAsync(cursor, 0, (size_t)NN * 4, stream);
    hipMemsetAsync(bnst, 0, (size_t)3 * 2 * NBKT * 128 * 4, stream);
    hipMemsetAsync(gout, 0, (size_t)NG * 384 * 4, stream);

    int nbN = (NN + 255) / 256;     // 391
    int nbE = (NE + 255) / 256;     // 6250

    k_hist<<<nbE, 256, 0, stream>>>(dst, deg);
    k_dinv<<<nbN, 256, 0, stream>>>(deg, dinv);
    k_blockscan<<<nbN, 256, 0, stream>>>(deg, row_start, bsum);
    k_scanb<<<1, 512, 0, stream>>>(bsum, nbN, row_start);
    k_scanadd<<<nbN, 256, 0, stream>>>(row_start, bsum);
    k_fill<<<nbE, 256, 0, stream>>>(src, dst, dinv, row_start, cursor, epair);
    k_cast<<<(NN * 16 + 255) / 256, 256, 0, stream>>>(x, (uint4*)xb);
    for (int l = 0; l < 3; ++l) k_wfrag<<<32, 64, 0, stream>>>(W[l], Wf + l * 16384);

    for (int l = 0; l < 3; ++l) {
        float* S = bnst + (size_t)l * 2 * NBKT * 128;
        float* Q = S + NBKT * 128;
        float* sv = svt + l * 256;
        float* tv = sv + 128;
        const ushort* gin = (l == 0) ? xb : act;
        const ushort* wfrag = (l == 0) ? (Wf + 0) : Wff;
        const float* tw_in = (l == 0) ? nullptr : tW;

        k_gemm<<<(NN + 63) / 64, 256, 0, stream>>>(gin, wfrag, tw_in, hm);
        k_agg<<<AGG_BLOCKS, 256, 0, stream>>>((const uint*)hm, epair, row_start, dinv, b[l],
                                              (uint*)act, S, Q);
        k_finalize<<<1, 128, 0, stream>>>(S, Q, g[l], beta[l], sv, tv,
                                          (l < 2) ? W[l + 1] : nullptr, tW);
        if (l < 2) k_wscale<<<32, 64, 0, stream>>>(Wf + (l + 1) * 16384, sv, Wff);
        k_norm<<<(NN + 63) / 64, 128, 0, stream>>>(act, sv, tv, batch, out, gout, l * 128);
    }
}

// Round 6
// 546.489 us; speedup vs baseline: 1.8214x; 1.0187x over previous
//
#include <hip/hip_runtime.h>

#define NN 100000
#define NE 1600000
#define NG 128
#define BN_EPS 1e-5f
#define NBKT 64
#define AGG_BLOCKS 2048
#define AGG_WAVES (AGG_BLOCKS * 4)
#define NPART 8
#define PSIZE 12500   // NN / NPART, exact
#define CSR_BLOCKS 2048

typedef short s16x8 __attribute__((ext_vector_type(8)));
typedef float f32x4 __attribute__((ext_vector_type(4)));

static __device__ __forceinline__ unsigned short f2bf(float f) {
    unsigned u = __float_as_uint(f);
    u += 0x7fffu + ((u >> 16) & 1u);   // RNE
    return (unsigned short)(u >> 16);
}
static __device__ __forceinline__ unsigned packbf(float a, float b) {
    return (unsigned)f2bf(a) | ((unsigned)f2bf(b) << 16);
}
static __device__ __forceinline__ float bf_lo(unsigned u) { return __uint_as_float(u << 16); }
static __device__ __forceinline__ float bf_hi(unsigned u) { return __uint_as_float(u & 0xffff0000u); }
static __device__ __forceinline__ float bf2f(ushort u) { return __uint_as_float((unsigned)u << 16); }

// ---------------- degree histogram (XCD-partitioned by dst range) ----------------
__global__ __launch_bounds__(256) void k_hist(const int* __restrict__ dst, int* __restrict__ deg) {
    int grp = blockIdx.x & (NPART - 1);
    int bg = blockIdx.x >> 3;
    int nbg = gridDim.x >> 3;
    int lo = grp * PSIZE, hi = lo + PSIZE;
    for (int e = bg * 256 + threadIdx.x; e < NE; e += nbg * 256) {
        int d = dst[e];
        if (d >= lo && d < hi) atomicAdd(&deg[d], 1);
    }
}

__global__ __launch_bounds__(256) void k_dinv(const int* __restrict__ deg, float* __restrict__ dinv) {
    int n = blockIdx.x * 256 + threadIdx.x;
    if (n < NN) dinv[n] = rsqrtf((float)deg[n] + 1.0f);
}

// ---------------- prefix scan over deg -> row_start ----------------
__global__ __launch_bounds__(256) void k_blockscan(const int* __restrict__ deg, int* __restrict__ excl,
                                                   int* __restrict__ bsum) {
    __shared__ int s[256];
    int t = threadIdx.x;
    int i = blockIdx.x * 256 + t;
    int v = (i < NN) ? deg[i] : 0;
    s[t] = v;
    __syncthreads();
    for (int o = 1; o < 256; o <<= 1) {
        int add = (t >= o) ? s[t - o] : 0;
        __syncthreads();
        s[t] += add;
        __syncthreads();
    }
    if (i < NN) excl[i] = s[t] - v;
    if (t == 255) bsum[blockIdx.x] = s[255];
}

__global__ __launch_bounds__(512) void k_scanb(int* __restrict__ bsum, int nb, int* __restrict__ row_start) {
    __shared__ int s[512];
    int t = threadIdx.x;
    int v = (t < nb) ? bsum[t] : 0;
    s[t] = v;
    __syncthreads();
    for (int o = 1; o < 512; o <<= 1) {
        int add = (t >= o) ? s[t - o] : 0;
        __syncthreads();
        s[t] += add;
        __syncthreads();
    }
    if (t < nb) bsum[t] = s[t] - v;
    if (t == nb - 1) row_start[NN] = s[t];
}

__global__ __launch_bounds__(256) void k_scanadd(int* __restrict__ row_start, const int* __restrict__ bsum) {
    int i = blockIdx.x * 256 + threadIdx.x;
    if (i < NN) row_start[i] += bsum[blockIdx.x];
}

// ---------------- CSR fill (XCD-partitioned by dst range) ----------------
__global__ __launch_bounds__(256) void k_fill(const int* __restrict__ src, const int* __restrict__ dst,
                                              const float* __restrict__ dinv, const int* __restrict__ row_start,
                                              int* __restrict__ cursor, int2* __restrict__ epair) {
    int grp = blockIdx.x & (NPART - 1);
    int bg = blockIdx.x >> 3;
    int nbg = gridDim.x >> 3;
    int lo = grp * PSIZE, hi = lo + PSIZE;
    for (int e = bg * 256 + threadIdx.x; e < NE; e += nbg * 256) {
        int d = dst[e];
        if (d >= lo && d < hi) {
            int s = src[e];
            float cf = dinv[s] * dinv[d];
            int pos = row_start[d] + atomicAdd(&cursor[d], 1);
            epair[pos] = make_int2(s, __float_as_int(cf));
        }
    }
}

// ---------------- x -> bf16 cast ----------------
__global__ __launch_bounds__(256) void k_cast(const float* __restrict__ x, uint4* __restrict__ xb) {
    int i = blockIdx.x * 256 + threadIdx.x;   // 1.6M groups of 8 floats
    if (i >= NN * 16) return;
    float4 a = *(const float4*)(x + (size_t)i * 8);
    float4 b = *(const float4*)(x + (size_t)i * 8 + 4);
    uint4 o;
    o.x = packbf(a.x, a.y);
    o.y = packbf(a.z, a.w);
    o.z = packbf(b.x, b.y);
    o.w = packbf(b.z, b.w);
    xb[i] = o;
}

// ---------------- W -> MFMA fragment order (bf16) ----------------
// Wf[((ks*8+nb)*64 + lane)*8 + j] = bf16(W[ks*32 + (lane>>4)*8 + j][nb*16 + (lane&15)])
__global__ __launch_bounds__(64) void k_wfrag(const float* __restrict__ W, ushort* __restrict__ Wf) {
    int unit = blockIdx.x;          // 0..31: ks = unit>>3, nb = unit&7
    int lane = threadIdx.x;
    int ks = unit >> 3, nb = unit & 7;
    int n = nb * 16 + (lane & 15);
    int k0 = ks * 32 + (lane >> 4) * 8;
    ushort o[8];
#pragma unroll
    for (int j = 0; j < 8; ++j) o[j] = f2bf(W[(size_t)(k0 + j) * 128 + n]);
    ushort* p = Wf + ((size_t)unit * 64 + lane) * 8;
#pragma unroll
    for (int j = 0; j < 8; ++j) p[j] = o[j];
}

// ---------------- fold BN scale into W fragments: Wff = diag(s) * W (bf16) ----------------
__global__ __launch_bounds__(64) void k_wscale(const ushort* __restrict__ Wfb, const float* __restrict__ svec,
                                               ushort* __restrict__ Wff) {
    int unit = blockIdx.x;
    int lane = threadIdx.x;
    int k0 = (unit >> 3) * 32 + (lane >> 4) * 8;
    const ushort* p = Wfb + ((size_t)unit * 64 + lane) * 8;
    ushort* o = Wff + ((size_t)unit * 64 + lane) * 8;
#pragma unroll
    for (int j = 0; j < 8; ++j) o[j] = f2bf(bf2f(p[j]) * svec[k0 + j]);
}

// ---------------- BN stats -> (scale, shift), and tW = shift^T @ Wnext ----------------
__global__ __launch_bounds__(128) void k_finalize(const float* __restrict__ S, const float* __restrict__ Q,
                                                  const float* __restrict__ gam, const float* __restrict__ bet,
                                                  float* __restrict__ svec, float* __restrict__ tvec,
                                                  const float* __restrict__ Wnext, float* __restrict__ tW) {
    __shared__ float ts[128];
    int c = threadIdx.x;
    float s = 0.f, q = 0.f;
    for (int k = 0; k < NBKT; ++k) {
        s += S[k * 128 + c];
        q += Q[k * 128 + c];
    }
    float mean = s / (float)NN;
    float var = q / (float)NN - mean * mean;
    float rstd = rsqrtf(fmaxf(var, 0.f) + BN_EPS);
    float sc = gam[c] * rstd;
    float sh = bet[c] - mean * sc;
    svec[c] = sc;
    tvec[c] = sh;
    ts[c] = sh;
    __syncthreads();
    if (Wnext) {
        float acc = 0.f;
        for (int k = 0; k < 128; ++k) acc += ts[k] * Wnext[(size_t)k * 128 + c];
        tW[c] = acc;
    }
}

// ---------------- MFMA GEMM: hm_bf16[N][128] = Xb_bf16[N][128] @ Wf (+ tW row vector) ----------------
__global__ __launch_bounds__(256) void k_gemm(const ushort* __restrict__ Xb, const ushort* __restrict__ Wf,
                                              const float* __restrict__ tW, ushort* __restrict__ hm) {
    int tid = threadIdx.x;
    int wid = tid >> 6, lane = tid & 63;
    int r0 = blockIdx.x * 64 + wid * 16;
    int m = lane & 15, g = lane >> 4;
    int xrow = r0 + m;
    int xr = (xrow < NN) ? xrow : (NN - 1);
    const ushort* Xrow = Xb + (size_t)xr * 128 + g * 8;
    f32x4 acc[8];
#pragma unroll
    for (int nb = 0; nb < 8; ++nb) acc[nb] = (f32x4){0.f, 0.f, 0.f, 0.f};
#pragma unroll
    for (int ks = 0; ks < 4; ++ks) {
        s16x8 af = *(const s16x8*)(Xrow + ks * 32);
#pragma unroll
        for (int nb = 0; nb < 8; ++nb) {
            s16x8 wf = *(const s16x8*)(Wf + ((size_t)(ks * 8 + nb) * 64 + lane) * 8);
            acc[nb] = __builtin_amdgcn_mfma_f32_16x16x32_bf16(wf, af, acc[nb], 0, 0, 0);
        }
    }
    if (xrow < NN) {
        ushort* orow = hm + (size_t)xrow * 128 + g * 4;
        if (tW) {
#pragma unroll
            for (int nb = 0; nb < 8; ++nb) {
                float4 tw = *(const float4*)(tW + nb * 16 + g * 4);
                ushort4 o;
                o.x = f2bf(acc[nb][0] + tw.x);
                o.y = f2bf(acc[nb][1] + tw.y);
                o.z = f2bf(acc[nb][2] + tw.z);
                o.w = f2bf(acc[nb][3] + tw.w);
                *(ushort4*)(orow + nb * 16) = o;
            }
        } else {
#pragma unroll
            for (int nb = 0; nb < 8; ++nb) {
                ushort4 o;
                o.x = f2bf(acc[nb][0]);
                o.y = f2bf(acc[nb][1]);
                o.z = f2bf(acc[nb][2]);
                o.w = f2bf(acc[nb][3]);
                *(ushort4*)(orow + nb * 16) = o;
            }
        }
    }
}

// ---------------- aggregate + bias + relu + fused BN stats ----------------
// Persistent: one wave per node per iteration; lane covers 2 channels (dword of 256B row).
// Per-thread stat registers across nodes -> LDS reduce -> bucketed global atomics.
__global__ __launch_bounds__(256) void k_agg(const uint* __restrict__ hm32, const int2* __restrict__ epair,
                                             const int* __restrict__ rs, const float* __restrict__ dinv,
                                             const float* __restrict__ bias, uint* __restrict__ act,
                                             float* __restrict__ bnsum, float* __restrict__ bnsq) {
    __shared__ float ls[128], lq[128];
    int tid = threadIdx.x;
    if (tid < 128) { ls[tid] = 0.f; lq[tid] = 0.f; }
    __syncthreads();
    int lane = tid & 63;
    int wgid = blockIdx.x * 4 + (tid >> 6);
    float2 b2 = *(const float2*)(bias + lane * 2);
    float s0 = 0.f, s1 = 0.f, q0 = 0.f, q1 = 0.f;

    for (int n = wgid; n < NN; n += AGG_WAVES) {
        float di = dinv[n];
        float sc = di * di;
        uint self = hm32[(size_t)n * 64 + lane];
        float a0 = sc * bf_lo(self);
        float a1 = sc * bf_hi(self);

        int i  = __builtin_amdgcn_readfirstlane(rs[n]);
        int i1 = __builtin_amdgcn_readfirstlane(rs[n + 1]);

        int2 epv = make_int2(0, 0);
        if (i < i1) {
            int o = min(min(lane, 15), i1 - i - 1);
            epv = epair[i + o];
        }
        while (i < i1) {
            int cnt = i1 - i;
            cnt = (cnt > 16) ? 16 : cnt;       // wave-uniform
            int2 cur = epv;
            int inext = i + cnt;
            if (inext < i1) {                   // prefetch next chunk while gathers fly
                int o = min(min(lane, 15), i1 - inext - 1);
                epv = epair[inext + o];
            }
            uint g[16];
#pragma unroll
            for (int u = 0; u < 16; ++u) {
                int sidx = __builtin_amdgcn_readlane(cur.x, min(u, cnt - 1));
                g[u] = hm32[(size_t)sidx * 64 + lane];
            }
#pragma unroll
            for (int u = 0; u < 16; ++u) {
                float c = __int_as_float(__builtin_amdgcn_readlane(cur.y, min(u, cnt - 1)));
                c = (u < cnt) ? c : 0.f;
                a0 += c * bf_lo(g[u]);
                a1 += c * bf_hi(g[u]);
            }
            i = inext;
        }
        float z0 = fmaxf(a0 + b2.x, 0.f);
        float z1 = fmaxf(a1 + b2.y, 0.f);
        act[(size_t)n * 64 + lane] = packbf(z0, z1);
        s0 += z0; s1 += z1;
        q0 += z0 * z0; q1 += z1 * z1;
    }
    atomicAdd(&ls[lane * 2],     s0);
    atomicAdd(&ls[lane * 2 + 1], s1);
    atomicAdd(&lq[lane * 2],     q0);
    atomicAdd(&lq[lane * 2 + 1], q1);
    __syncthreads();
    if (tid < 128) {
        int bkt = blockIdx.x & (NBKT - 1);
        atomicAdd(&bnsum[bkt * 128 + tid], ls[tid]);
        atomicAdd(&bnsq[bkt * 128 + tid],  lq[tid]);
    }
}

// ---------------- normalize + write h_cat + pool ----------------
__global__ __launch_bounds__(128) void k_norm(const ushort* __restrict__ act, const float* __restrict__ svec,
                                              const float* __restrict__ tvec, const int* __restrict__ batch,
                                              float* __restrict__ out, float* __restrict__ gout, int lofs) {
    int c = threadIdx.x;
    int n0 = blockIdx.x * 64;
    if (n0 >= NN) return;
    int n1 = n0 + 64; if (n1 > NN) n1 = NN;
    float scale = svec[c];
    float shift = tvec[c];
    int cur = batch[n0];
    float acc = 0.f;
    for (int n = n0; n < n1; ++n) {
        float z = bf2f(act[(size_t)n * 128 + c]) * scale + shift;
        out[(size_t)n * 384 + lofs + c] = z;
        int bn = batch[n];
        if (bn != cur) {
            atomicAdd(&gout[(size_t)cur * 384 + lofs + c], acc);
            acc = 0.f;
            cur = bn;
        }
        acc += z;
    }
    atomicAdd(&gout[(size_t)cur * 384 + lofs + c], acc);
}

extern "C" void kernel_launch(void* const* d_in, const int* in_sizes, int n_in,
                              void* d_out, int out_size, void* d_ws, size_t ws_size,
                              hipStream_t stream) {
    const float* x = (const float*)d_in[0];
    const int* ei = (const int*)d_in[1];
    const int* src = ei;
    const int* dst = ei + NE;
    const int* batch = (const int*)d_in[2];
    const float *W[3], *b[3], *g[3], *beta[3];
    for (int l = 0; l < 3; ++l) {
        W[l]    = (const float*)d_in[3 + 4 * l];
        b[l]    = (const float*)d_in[4 + 4 * l];
        g[l]    = (const float*)d_in[5 + 4 * l];
        beta[l] = (const float*)d_in[6 + 4 * l];
    }
    float* out = (float*)d_out;
    float* gout = out + (size_t)NN * 384;

    char* ws = (char*)d_ws;
    size_t off = 0;
    auto alloc = [&](size_t bytes) -> char* {
        off = (off + 255) & ~(size_t)255;
        char* p = ws + off;
        off += bytes;
        return p;
    };
    ushort* xb       = (ushort*)alloc((size_t)NN * 256);      // bf16 x
    ushort* act      = (ushort*)alloc((size_t)NN * 256);      // bf16 relu output (pre-BN)
    ushort* hm       = (ushort*)alloc((size_t)NN * 256);      // bf16 gemm output
    int2*   epair    = (int2*)alloc((size_t)NE * 8);
    int*    deg      = (int*)alloc((size_t)NN * 4);
    int*    cursor   = (int*)alloc((size_t)NN * 4);
    int*    row_start= (int*)alloc((size_t)(NN + 1) * 4);
    float*  dinv     = (float*)alloc((size_t)NN * 4);
    int*    bsum     = (int*)alloc(512 * 4);
    float*  bnst     = (float*)alloc((size_t)3 * 2 * NBKT * 128 * 4);   // [layer][sum|sq][NBKT][128]
    ushort* Wf       = (ushort*)alloc(3 * 16384 * 2);
    ushort* Wff      = (ushort*)alloc(16384 * 2);
    float*  svt      = (float*)alloc(3 * 2 * 128 * 4);                  // [layer][s|t][128]
    float*  tW       = (float*)alloc(128 * 4);
    (void)ws_size;

    hipMemsetAsync(deg, 0, (size_t)NN * 4, stream);
    hipMemsetAsync(cursor, 0, (size_t)NN * 4, stream);
    hipMemsetAsync(bnst, 0, (size_t)3 * 2 * NBKT * 128 * 4, stream);
    hipMemsetAsync(gout, 0, (size_t)NG * 384 * 4, stream);

    int nbN = (NN + 255) / 256;     // 391

    k_hist<<<CSR_BLOCKS, 256, 0, stream>>>(dst, deg);
    k_dinv<<<nbN, 256, 0, stream>>>(deg, dinv);
    k_blockscan<<<nbN, 256, 0, stream>>>(deg, row_start, bsum);
    k_scanb<<<1, 512, 0, stream>>>(bsum, nbN, row_start);
    k_scanadd<<<nbN, 256, 0, stream>>>(row_start, bsum);
    k_fill<<<CSR_BLOCKS, 256, 0, stream>>>(src, dst, dinv, row_start, cursor, epair);
    k_cast<<<(NN * 16 + 255) / 256, 256, 0, stream>>>(x, (uint4*)xb);
    for (int l = 0; l < 3; ++l) k_wfrag<<<32, 64, 0, stream>>>(W[l], Wf + l * 16384);

    for (int l = 0; l < 3; ++l) {
        float* S = bnst + (size_t)l * 2 * NBKT * 128;
        float* Q = S + NBKT * 128;
        float* sv = svt + l * 256;
        float* tv = sv + 128;
        const ushort* gin = (l == 0) ? xb : act;
        const ushort* wfrag = (l == 0) ? (Wf + 0) : Wff;
        const float* tw_in = (l == 0) ? nullptr : tW;

        k_gemm<<<(NN + 63) / 64, 256, 0, stream>>>(gin, wfrag, tw_in, hm);
        k_agg<<<AGG_BLOCKS, 256, 0, stream>>>((const uint*)hm, epair, row_start, dinv, b[l],
                                              (uint*)act, S, Q);
        k_finalize<<<1, 128, 0, stream>>>(S, Q, g[l], beta[l], sv, tv,
                                          (l < 2) ? W[l + 1] : nullptr, tW);
        if (l < 2) k_wscale<<<32, 64, 0, stream>>>(Wf + (l + 1) * 16384, sv, Wff);
        k_norm<<<(NN + 63) / 64, 128, 0, stream>>>(act, sv, tv, batch, out, gout, l * 128);
    }
}

// Round 7
// 473.120 us; speedup vs baseline: 2.1039x; 1.1551x over previous
//
#include <hip/hip_runtime.h>

#define NN 100000
#define NE 1600000
#define NG 128
#define BN_EPS 1e-5f
#define NBKT 64
#define AGG_BLOCKS 2048
#define AGG_WAVES (AGG_BLOCKS * 4)
#define NBUCK 98          // ceil(NN / 1024)
#define BIN_BLOCKS 256
#define BIN_CHUNK 6250    // NE / BIN_BLOCKS exact

typedef short s16x8 __attribute__((ext_vector_type(8)));
typedef float f32x4 __attribute__((ext_vector_type(4)));

static __device__ __forceinline__ unsigned short f2bf(float f) {
    unsigned u = __float_as_uint(f);
    u += 0x7fffu + ((u >> 16) & 1u);   // RNE
    return (unsigned short)(u >> 16);
}
static __device__ __forceinline__ unsigned packbf(float a, float b) {
    return (unsigned)f2bf(a) | ((unsigned)f2bf(b) << 16);
}
static __device__ __forceinline__ float bf_lo(unsigned u) { return __uint_as_float(u << 16); }
static __device__ __forceinline__ float bf_hi(unsigned u) { return __uint_as_float(u & 0xffff0000u); }
static __device__ __forceinline__ float bf2f(ushort u) { return __uint_as_float((unsigned)u << 16); }

// ---------------- pass 0: coarse bucket histogram ----------------
__global__ __launch_bounds__(256) void k_bhist(const int* __restrict__ dst, int* __restrict__ gbh) {
    __shared__ int lh[128];
    int t = threadIdx.x;
    if (t < 128) lh[t] = 0;
    __syncthreads();
    for (int e = blockIdx.x * 256 + t; e < NE; e += gridDim.x * 256)
        atomicAdd(&lh[dst[e] >> 10], 1);
    __syncthreads();
    if (t < 128 && lh[t]) atomicAdd(&gbh[t], lh[t]);
}

// ---------------- bucket base scan (1 block) ----------------
__global__ __launch_bounds__(128) void k_bscan(const int* __restrict__ gbh, int* __restrict__ gbase,
                                               int* __restrict__ gcur, int* __restrict__ row_start) {
    __shared__ int s[128];
    int t = threadIdx.x;
    int v = gbh[t];
    s[t] = v;
    __syncthreads();
    for (int o = 1; o < 128; o <<= 1) {
        int a = (t >= o) ? s[t - o] : 0;
        __syncthreads();
        s[t] += a;
        __syncthreads();
    }
    int ex = s[t] - v;
    gbase[t] = ex;
    gcur[t] = ex;
    if (t == 127) { gbase[128] = s[127]; row_start[NN] = NE; }
}

// ---------------- pass 1: bin edges into bucket regions (time-dense writes) ----------------
__global__ __launch_bounds__(256) void k_bin(const int* __restrict__ src, const int* __restrict__ dst,
                                             int* __restrict__ gcur, int* __restrict__ tmp) {
    __shared__ int lh[128], lb[128], lc[128];
    int t = threadIdx.x;
    if (t < 128) lh[t] = 0;
    __syncthreads();
    int e0 = blockIdx.x * BIN_CHUNK, e1 = e0 + BIN_CHUNK;
    for (int e = e0 + t; e < e1; e += 256) atomicAdd(&lh[dst[e] >> 10], 1);
    __syncthreads();
    if (t < 128) {
        int c = lh[t];
        lb[t] = c ? atomicAdd(&gcur[t], c) : 0;
        lc[t] = 0;
    }
    __syncthreads();
    for (int e = e0 + t; e < e1; e += 256) {
        int d = dst[e];
        int b = d >> 10;
        int off = atomicAdd(&lc[b], 1);
        tmp[lb[b] + off] = (src[e] << 10) | (d & 1023);   // src:17b | dst_lo:10b
    }
}

// ---------------- pass 2: per-bucket counting sort -> esrc, row_start, dinv ----------------
__global__ __launch_bounds__(256) void k_csr(const int* __restrict__ tmp, const int* __restrict__ gbase,
                                             int* __restrict__ esrc, int* __restrict__ row_start,
                                             float* __restrict__ dinv) {
    __shared__ int h[1024], hs[1024], part[256];
    int b = blockIdx.x, t = threadIdx.x;
    int base = gbase[b], end = gbase[b + 1];
#pragma unroll
    for (int k = 0; k < 4; ++k) h[t * 4 + k] = 0;
    __syncthreads();
    for (int i = base + t; i < end; i += 256) atomicAdd(&h[tmp[i] & 1023], 1);
    __syncthreads();
    int l0 = h[t * 4], l1 = h[t * 4 + 1], l2 = h[t * 4 + 2], l3 = h[t * 4 + 3];
    int ssum = l0 + l1 + l2 + l3;
    part[t] = ssum;
    __syncthreads();
    for (int o = 1; o < 256; o <<= 1) {
        int a = (t >= o) ? part[t - o] : 0;
        __syncthreads();
        part[t] += a;
        __syncthreads();
    }
    int ex = part[t] - ssum;
    hs[t * 4]     = ex;
    hs[t * 4 + 1] = ex + l0;
    hs[t * 4 + 2] = ex + l0 + l1;
    hs[t * 4 + 3] = ex + l0 + l1 + l2;
    int n0 = b * 1024 + t * 4;
#pragma unroll
    for (int k = 0; k < 4; ++k) {
        int n = n0 + k;
        if (n < NN) {
            row_start[n] = base + hs[t * 4 + k];
            dinv[n] = rsqrtf((float)h[t * 4 + k] + 1.0f);
        }
    }
    __syncthreads();
    for (int i = base + t; i < end; i += 256) {
        int rec = tmp[i];
        int pos = atomicAdd(&hs[rec & 1023], 1);
        esrc[base + pos] = rec >> 10;
    }
}

// ---------------- x -> bf16 cast ----------------
__global__ __launch_bounds__(256) void k_cast(const float* __restrict__ x, uint4* __restrict__ xb) {
    int i = blockIdx.x * 256 + threadIdx.x;
    if (i >= NN * 16) return;
    float4 a = *(const float4*)(x + (size_t)i * 8);
    float4 b = *(const float4*)(x + (size_t)i * 8 + 4);
    uint4 o;
    o.x = packbf(a.x, a.y);
    o.y = packbf(a.z, a.w);
    o.z = packbf(b.x, b.y);
    o.w = packbf(b.z, b.w);
    xb[i] = o;
}

// ---------------- W -> MFMA fragment order (bf16) ----------------
__global__ __launch_bounds__(64) void k_wfrag(const float* __restrict__ W, ushort* __restrict__ Wf) {
    int unit = blockIdx.x;          // 0..31: ks = unit>>3, nb = unit&7
    int lane = threadIdx.x;
    int ks = unit >> 3, nb = unit & 7;
    int n = nb * 16 + (lane & 15);
    int k0 = ks * 32 + (lane >> 4) * 8;
    ushort o[8];
#pragma unroll
    for (int j = 0; j < 8; ++j) o[j] = f2bf(W[(size_t)(k0 + j) * 128 + n]);
    ushort* p = Wf + ((size_t)unit * 64 + lane) * 8;
#pragma unroll
    for (int j = 0; j < 8; ++j) p[j] = o[j];
}

// ---------------- fold BN scale into W fragments: Wff = diag(s) * W (bf16) ----------------
__global__ __launch_bounds__(64) void k_wscale(const ushort* __restrict__ Wfb, const float* __restrict__ svec,
                                               ushort* __restrict__ Wff) {
    int unit = blockIdx.x;
    int lane = threadIdx.x;
    int k0 = (unit >> 3) * 32 + (lane >> 4) * 8;
    const ushort* p = Wfb + ((size_t)unit * 64 + lane) * 8;
    ushort* o = Wff + ((size_t)unit * 64 + lane) * 8;
#pragma unroll
    for (int j = 0; j < 8; ++j) o[j] = f2bf(bf2f(p[j]) * svec[k0 + j]);
}

// ---------------- BN stats -> (scale, shift), and tW = shift^T @ Wnext ----------------
__global__ __launch_bounds__(128) void k_finalize(const float* __restrict__ S, const float* __restrict__ Q,
                                                  const float* __restrict__ gam, const float* __restrict__ bet,
                                                  float* __restrict__ svec, float* __restrict__ tvec,
                                                  const float* __restrict__ Wnext, float* __restrict__ tW) {
    __shared__ float ts[128];
    int c = threadIdx.x;
    float s = 0.f, q = 0.f;
    for (int k = 0; k < NBKT; ++k) {
        s += S[k * 128 + c];
        q += Q[k * 128 + c];
    }
    float mean = s / (float)NN;
    float var = q / (float)NN - mean * mean;
    float rstd = rsqrtf(fmaxf(var, 0.f) + BN_EPS);
    float sc = gam[c] * rstd;
    float sh = bet[c] - mean * sc;
    svec[c] = sc;
    tvec[c] = sh;
    ts[c] = sh;
    __syncthreads();
    if (Wnext) {
        float acc = 0.f;
        for (int k = 0; k < 128; ++k) acc += ts[k] * Wnext[(size_t)k * 128 + c];
        tW[c] = acc;
    }
}

// ---------------- MFMA GEMM: hm'[N][128] = dinv[row] * (Xb @ Wf + tW) ----------------
__global__ __launch_bounds__(256) void k_gemm(const ushort* __restrict__ Xb, const ushort* __restrict__ Wf,
                                              const float* __restrict__ tW, const float* __restrict__ dinv,
                                              ushort* __restrict__ hm) {
    int tid = threadIdx.x;
    int wid = tid >> 6, lane = tid & 63;
    int r0 = blockIdx.x * 64 + wid * 16;
    int m = lane & 15, g = lane >> 4;
    int xrow = r0 + m;
    int xr = (xrow < NN) ? xrow : (NN - 1);
    const ushort* Xrow = Xb + (size_t)xr * 128 + g * 8;
    f32x4 acc[8];
#pragma unroll
    for (int nb = 0; nb < 8; ++nb) acc[nb] = (f32x4){0.f, 0.f, 0.f, 0.f};
#pragma unroll
    for (int ks = 0; ks < 4; ++ks) {
        s16x8 af = *(const s16x8*)(Xrow + ks * 32);
#pragma unroll
        for (int nb = 0; nb < 8; ++nb) {
            s16x8 wf = *(const s16x8*)(Wf + ((size_t)(ks * 8 + nb) * 64 + lane) * 8);
            acc[nb] = __builtin_amdgcn_mfma_f32_16x16x32_bf16(wf, af, acc[nb], 0, 0, 0);
        }
    }
    if (xrow < NN) {
        float ds = dinv[xr];
        ushort* orow = hm + (size_t)xrow * 128 + g * 4;
        if (tW) {
#pragma unroll
            for (int nb = 0; nb < 8; ++nb) {
                float4 tw = *(const float4*)(tW + nb * 16 + g * 4);
                ushort4 o;
                o.x = f2bf(ds * (acc[nb][0] + tw.x));
                o.y = f2bf(ds * (acc[nb][1] + tw.y));
                o.z = f2bf(ds * (acc[nb][2] + tw.z));
                o.w = f2bf(ds * (acc[nb][3] + tw.w));
                *(ushort4*)(orow + nb * 16) = o;
            }
        } else {
#pragma unroll
            for (int nb = 0; nb < 8; ++nb) {
                ushort4 o;
                o.x = f2bf(ds * acc[nb][0]);
                o.y = f2bf(ds * acc[nb][1]);
                o.z = f2bf(ds * acc[nb][2]);
                o.w = f2bf(ds * acc[nb][3]);
                *(ushort4*)(orow + nb * 16) = o;
            }
        }
    }
}

// ---------------- aggregate + bias + relu + fused BN stats ----------------
// Persistent, one wave per node per iteration. hm' rows carry dinv[src] folded in:
// agg[d] = dinv[d] * (hm'[d] + sum hm'[s]). Pure sum — no per-edge coef.
// Padded gather slots read the guaranteed-zero row at hm[NN].
__global__ __launch_bounds__(256) void k_agg(const uint* __restrict__ hm32, const int* __restrict__ esrc,
                                             const int* __restrict__ rs, const float* __restrict__ dinv,
                                             const float* __restrict__ bias, uint* __restrict__ act,
                                             float* __restrict__ bnsum, float* __restrict__ bnsq) {
    __shared__ float ls[128], lq[128];
    int tid = threadIdx.x;
    if (tid < 128) { ls[tid] = 0.f; lq[tid] = 0.f; }
    __syncthreads();
    int lane = tid & 63;
    int wgid = blockIdx.x * 4 + (tid >> 6);
    float2 b2 = *(const float2*)(bias + lane * 2);
    float s0 = 0.f, s1 = 0.f, q0 = 0.f, q1 = 0.f;

    for (int n = wgid; n < NN; n += AGG_WAVES) {
        uint self = hm32[(size_t)n * 64 + lane];
        float a0 = bf_lo(self);
        float a1 = bf_hi(self);

        int i  = __builtin_amdgcn_readfirstlane(rs[n]);
        int i1 = __builtin_amdgcn_readfirstlane(rs[n + 1]);

        int idxv = 0;
        if (i < i1) idxv = esrc[i + min(min(lane, 15), i1 - i - 1)];

        while (i < i1) {
            int cnt = i1 - i;
            cnt = (cnt > 16) ? 16 : cnt;       // wave-uniform
            int cur = idxv;
            int inext = i + cnt;
            if (inext < i1)                    // prefetch next chunk while gathers fly
                idxv = esrc[inext + min(min(lane, 15), i1 - inext - 1)];
            uint g[16];
#pragma unroll
            for (int u = 0; u < 16; ++u) {
                int sidx = __builtin_amdgcn_readlane(cur, u);
                sidx = (u < cnt) ? sidx : NN;  // scalar select -> zero row for pads
                g[u] = hm32[(size_t)sidx * 64 + lane];
            }
#pragma unroll
            for (int u = 0; u < 16; ++u) {
                a0 += bf_lo(g[u]);
                a1 += bf_hi(g[u]);
            }
            i = inext;
        }
        float di = dinv[n];
        float z0 = fmaxf(fmaf(di, a0, b2.x), 0.f);
        float z1 = fmaxf(fmaf(di, a1, b2.y), 0.f);
        act[(size_t)n * 64 + lane] = packbf(z0, z1);
        s0 += z0; s1 += z1;
        q0 += z0 * z0; q1 += z1 * z1;
    }
    atomicAdd(&ls[lane * 2],     s0);
    atomicAdd(&ls[lane * 2 + 1], s1);
    atomicAdd(&lq[lane * 2],     q0);
    atomicAdd(&lq[lane * 2 + 1], q1);
    __syncthreads();
    if (tid < 128) {
        int bkt = blockIdx.x & (NBKT - 1);
        atomicAdd(&bnsum[bkt * 128 + tid], ls[tid]);
        atomicAdd(&bnsq[bkt * 128 + tid],  lq[tid]);
    }
}

// ---------------- normalize + write h_cat + pool ----------------
__global__ __launch_bounds__(128) void k_norm(const ushort* __restrict__ act, const float* __restrict__ svec,
                                              const float* __restrict__ tvec, const int* __restrict__ batch,
                                              float* __restrict__ out, float* __restrict__ gout, int lofs) {
    int c = threadIdx.x;
    int n0 = blockIdx.x * 64;
    if (n0 >= NN) return;
    int n1 = n0 + 64; if (n1 > NN) n1 = NN;
    float scale = svec[c];
    float shift = tvec[c];
    int cur = batch[n0];
    float acc = 0.f;
    for (int n = n0; n < n1; ++n) {
        float z = bf2f(act[(size_t)n * 128 + c]) * scale + shift;
        out[(size_t)n * 384 + lofs + c] = z;
        int bn = batch[n];
        if (bn != cur) {
            atomicAdd(&gout[(size_t)cur * 384 + lofs + c], acc);
            acc = 0.f;
            cur = bn;
        }
        acc += z;
    }
    atomicAdd(&gout[(size_t)cur * 384 + lofs + c], acc);
}

extern "C" void kernel_launch(void* const* d_in, const int* in_sizes, int n_in,
                              void* d_out, int out_size, void* d_ws, size_t ws_size,
                              hipStream_t stream) {
    const float* x = (const float*)d_in[0];
    const int* ei = (const int*)d_in[1];
    const int* src = ei;
    const int* dst = ei + NE;
    const int* batch = (const int*)d_in[2];
    const float *W[3], *b[3], *g[3], *beta[3];
    for (int l = 0; l < 3; ++l) {
        W[l]    = (const float*)d_in[3 + 4 * l];
        b[l]    = (const float*)d_in[4 + 4 * l];
        g[l]    = (const float*)d_in[5 + 4 * l];
        beta[l] = (const float*)d_in[6 + 4 * l];
    }
    float* out = (float*)d_out;
    float* gout = out + (size_t)NN * 384;

    char* ws = (char*)d_ws;
    size_t off = 0;
    auto alloc = [&](size_t bytes) -> char* {
        off = (off + 255) & ~(size_t)255;
        char* p = ws + off;
        off += bytes;
        return p;
    };
    ushort* xb       = (ushort*)alloc((size_t)NN * 256);        // bf16 x
    ushort* act      = (ushort*)alloc((size_t)NN * 256);        // bf16 relu output (pre-BN)
    ushort* hm       = (ushort*)alloc((size_t)(NN + 1) * 256);  // bf16 hm' rows + zero row at NN
    int*    esrc     = (int*)alloc((size_t)NE * 4);
    int*    tmp      = (int*)alloc((size_t)NE * 4);
    int*    row_start= (int*)alloc((size_t)(NN + 1) * 4);
    float*  dinv     = (float*)alloc((size_t)NN * 4);
    float*  bnst     = (float*)alloc((size_t)3 * 2 * NBKT * 128 * 4);   // [layer][sum|sq][NBKT][128]
    ushort* Wf       = (ushort*)alloc(3 * 16384 * 2);
    ushort* Wff      = (ushort*)alloc(16384 * 2);
    float*  svt      = (float*)alloc(3 * 2 * 128 * 4);                  // [layer][s|t][128]
    float*  tW       = (float*)alloc(128 * 4);
    int*    misc     = (int*)alloc(512 * 4);                            // gbh[128], gbase[129], gcur[128]
    int* gbh   = misc;
    int* gbase = misc + 128;
    int* gcur  = misc + 384;
    (void)ws_size;

    hipMemsetAsync(gbh, 0, 128 * 4, stream);
    hipMemsetAsync(hm + (size_t)NN * 128, 0, 256, stream);              // zero row
    hipMemsetAsync(bnst, 0, (size_t)3 * 2 * NBKT * 128 * 4, stream);
    hipMemsetAsync(gout, 0, (size_t)NG * 384 * 4, stream);

    k_bhist<<<512, 256, 0, stream>>>(dst, gbh);
    k_bscan<<<1, 128, 0, stream>>>(gbh, gbase, gcur, row_start);
    k_bin<<<BIN_BLOCKS, 256, 0, stream>>>(src, dst, gcur, tmp);
    k_csr<<<NBUCK, 256, 0, stream>>>(tmp, gbase, esrc, row_start, dinv);
    k_cast<<<(NN * 16 + 255) / 256, 256, 0, stream>>>(x, (uint4*)xb);
    for (int l = 0; l < 3; ++l) k_wfrag<<<32, 64, 0, stream>>>(W[l], Wf + l * 16384);

    for (int l = 0; l < 3; ++l) {
        float* S = bnst + (size_t)l * 2 * NBKT * 128;
        float* Q = S + NBKT * 128;
        float* sv = svt + l * 256;
        float* tv = sv + 128;
        const ushort* gin = (l == 0) ? xb : act;
        const ushort* wfrag = (l == 0) ? (Wf + 0) : Wff;
        const float* tw_in = (l == 0) ? nullptr : tW;

        k_gemm<<<(NN + 63) / 64, 256, 0, stream>>>(gin, wfrag, tw_in, dinv, hm);
        k_agg<<<AGG_BLOCKS, 256, 0, stream>>>((const uint*)hm, esrc, row_start, dinv, b[l],
                                              (uint*)act, S, Q);
        k_finalize<<<1, 128, 0, stream>>>(S, Q, g[l], beta[l], sv, tv,
                                          (l < 2) ? W[l + 1] : nullptr, tW);
        if (l < 2) k_wscale<<<32, 64, 0, stream>>>(Wf + (l + 1) * 16384, sv, Wff);
        k_norm<<<(NN + 63) / 64, 128, 0, stream>>>(act, sv, tv, batch, out, gout, l * 128);
    }
}